// Round 2
// baseline (714.627 us; speedup 1.0000x reference)
//
#include <hip/hip_runtime.h>
#include <math.h>

#define NN 500
#define BB 512

// Emulate the numpy float32 pipeline with correctly-rounded f32 ops:
//   uc -> l1 = f32(log(uc)); s = f32(1-uc); l2 = f32(log(s));
//   z = f32(la + f32(l1-l2)); y = f32(1/f32(1+f32(exp(-z)))); decision = y > 0.5
// f64 log/exp rounded to f32 == correctly-rounded f32 transcendentals.
__device__ __forceinline__ bool np_decision(float laf, float v) {
    float l1 = (float)log((double)v);
    float s  = 1.0f - v;              // f32 sub, exact HW rounding
    float l2 = (float)log((double)s);
    float logistic = l1 - l2;         // f32
    float z  = laf + logistic;        // f32
    float e  = (float)exp(-(double)z);
    float d  = 1.0f + e;              // f32
    float y  = 1.0f / d;              // f32 div, correctly rounded
    return y > 0.5f;                  // the f32 sigmoid plateau lives here
}

// Per-(j,i): find smallest f32 value U* in [LO,HI] with decision(la, U*) TRUE
// (chain is monotone nondecreasing in uc). Hot loop then tests uc >= U*.
// Also build transposed diagonal-zeroed weights Wt[j][i] = (i==j ? 0 : W[i][j]).
__global__ void prep_kernel(const float* __restrict__ la,
                            const float* __restrict__ W,
                            float* __restrict__ Ustar,
                            float* __restrict__ Wt) {
    int idx = blockIdx.x * blockDim.x + threadIdx.x;
    if (idx >= NN * NN) return;
    int j = idx / NN;
    int i = idx - j * NN;
    float laf = la[idx];

    const float LO = 1e-6f;                 // f32(1e-6), matches np.clip bound
    const float HI = (float)(1.0 - 1e-6);   // f32(0.999999)

    float U;
    if (!np_decision(laf, HI)) {
        U = __builtin_inff();               // never true
    } else if (np_decision(laf, LO)) {
        U = 0.0f;                           // always true (uc >= LO)
    } else {
        unsigned lo = __float_as_uint(LO);  // decision false here
        unsigned hi = __float_as_uint(HI);  // decision true here
        // Analytic threshold is within ~8 ulps of U*; bracket +-1024 ulps.
        double T  = 1.0 / (1.0 + exp((double)laf));
        float  Tf = fminf(fmaxf((float)T, LO), HI);
        unsigned g = __float_as_uint(Tf);
        unsigned a = (g > lo + 1024u) ? g - 1024u : lo;
        unsigned b = (g + 1024u < hi) ? g + 1024u : hi;
        if (!np_decision(laf, __uint_as_float(b))) {
            lo = b;                          // U* beyond window (rare)
        } else {
            hi = b;
            if (np_decision(laf, __uint_as_float(a))) hi = a; else lo = a;
        }
        while (hi - lo > 1u) {
            unsigned mid = lo + (hi - lo) / 2u;
            if (np_decision(laf, __uint_as_float(mid))) hi = mid; else lo = mid;
        }
        U = __uint_as_float(hi);
    }
    Ustar[idx] = U;
    Wt[idx] = (i == j) ? 0.0f : W[i * NN + j];
}

// One block per batch element b. 250 active threads, each owns output
// columns i = 2t, 2t+1. j-loop streams u[b,j,:] coalesced (float2/lane).
__global__ __launch_bounds__(256) void fused_kernel(
        const float* __restrict__ x,
        const float* __restrict__ u,
        const float* __restrict__ Ustar,
        const float* __restrict__ Wt,
        float* __restrict__ out) {
    __shared__ float xs[NN];
    const int b = blockIdx.x;
    const int t = threadIdx.x;
    for (int k = t; k < NN; k += 256) xs[k] = x[b * NN + k];
    __syncthreads();
    if (t >= NN / 2) return;

    const float2* __restrict__ u2 = (const float2*)(u + (size_t)b * NN * NN);
    const float2* __restrict__ w2 = (const float2*)Wt;
    const float2* __restrict__ t2 = (const float2*)Ustar;

    const float LO = 1e-6f;
    const float HI = (float)(1.0 - 1e-6);

    float acc0 = 0.0f, acc1 = 0.0f;
#pragma unroll 8
    for (int j = 0; j < NN; ++j) {
        const int k = j * (NN / 2) + t;
        float2 uv = u2[k];
        float2 wv = w2[k];
        float2 tv = t2[k];
        float  xj = xs[j];
        float uc0 = fminf(fmaxf(uv.x, LO), HI);
        float uc1 = fminf(fmaxf(uv.y, LO), HI);
        if (uc0 >= tv.x) acc0 += wv.x * xj;
        if (uc1 >= tv.y) acc1 += wv.y * xj;
    }
    float2 o;
    o.x = tanhf(acc0);
    o.y = tanhf(acc1);
    ((float2*)out)[b * (NN / 2) + t] = o;
}

extern "C" void kernel_launch(void* const* d_in, const int* in_sizes, int n_in,
                              void* d_out, int out_size, void* d_ws, size_t ws_size,
                              hipStream_t stream) {
    const float* x  = (const float*)d_in[0];   // [B, N]
    const float* la = (const float*)d_in[1];   // [N, N]
    const float* W  = (const float*)d_in[2];   // [N, N]
    const float* u  = (const float*)d_in[3];   // [B, N, N]
    float* out = (float*)d_out;                // [B, N]

    float* Ustar = (float*)d_ws;                               // 1,000,000 B
    float* Wt    = (float*)((char*)d_ws + (size_t)NN * NN * sizeof(float));

    int prep_blocks = (NN * NN + 255) / 256;
    prep_kernel<<<prep_blocks, 256, 0, stream>>>(la, W, Ustar, Wt);
    fused_kernel<<<BB, 256, 0, stream>>>(x, u, Ustar, Wt, out);
}

// Round 3
// 705.394 us; speedup vs baseline: 1.0131x; 1.0131x over previous
//
#include <hip/hip_runtime.h>
#include <math.h>

#define NN 500
#define BB 512
#define NCHUNK 4          // j-dimension split (125 rows per block)
#define JCH (NN / NCHUNK) // 125

// ---------------- prep: bit-exact f32 threshold + interleaved (W,U*) table ---
// Emulate numpy's float32 pipeline with correctly-rounded f32 ops:
//   uc -> l1=f32(log uc); s=f32(1-uc); l2=f32(log s);
//   z=f32(la+f32(l1-l2)); y=f32(1/f32(1+f32(exp(-z)))); decision = y > 0.5f
__device__ __forceinline__ bool np_decision(float laf, float v) {
    float l1 = (float)log((double)v);
    float s  = 1.0f - v;
    float l2 = (float)log((double)s);
    float logistic = l1 - l2;
    float z  = laf + logistic;
    float e  = (float)exp(-(double)z);
    float d  = 1.0f + e;
    float y  = 1.0f / d;
    return y > 0.5f;
}

// WU[j*NN+i] = { Wt, Ustar } where Wt = (i==j ? 0 : W[i][j]) and Ustar is the
// smallest f32 uc in [LO,HI] whose emulated-f32 decision is TRUE (monotone).
__global__ void prep_kernel(const float* __restrict__ la,
                            const float* __restrict__ W,
                            float2* __restrict__ WU) {
    int idx = blockIdx.x * blockDim.x + threadIdx.x;
    if (idx >= NN * NN) return;
    int j = idx / NN;
    int i = idx - j * NN;
    float laf = la[idx];

    const float LO = 1e-6f;
    const float HI = (float)(1.0 - 1e-6);

    float U;
    if (!np_decision(laf, HI)) {
        U = __builtin_inff();               // never true
    } else if (np_decision(laf, LO)) {
        U = 0.0f;                           // always true
    } else {
        unsigned lo = __float_as_uint(LO);
        unsigned hi = __float_as_uint(HI);
        double T  = 1.0 / (1.0 + exp((double)laf));
        float  Tf = fminf(fmaxf((float)T, LO), HI);
        unsigned g = __float_as_uint(Tf);
        unsigned a = (g > lo + 1024u) ? g - 1024u : lo;
        unsigned b = (g + 1024u < hi) ? g + 1024u : hi;
        if (!np_decision(laf, __uint_as_float(b))) {
            lo = b;
        } else {
            hi = b;
            if (np_decision(laf, __uint_as_float(a))) hi = a; else lo = a;
        }
        while (hi - lo > 1u) {
            unsigned mid = lo + (hi - lo) / 2u;
            if (np_decision(laf, __uint_as_float(mid))) hi = mid; else lo = mid;
        }
        U = __uint_as_float(hi);
    }
    float w = (i == j) ? 0.0f : W[i * NN + j];
    WU[idx] = make_float2(w, U);
}

// ---------------- fused: partial masked matvec over a 125-row j-chunk --------
// grid = BB * NCHUNK blocks (8 blocks/CU -> 32 waves/CU). Block (b, c) streams
// u[b, c*125 .. c*125+125, :] coalesced; one float4 WU load + one float2 u
// load per iteration. Partials into P[c][b][i].
__global__ __launch_bounds__(256) void fused_kernel(
        const float* __restrict__ x,
        const float* __restrict__ u,
        const float4* __restrict__ WU4,   // (w,U*) pairs, 2 columns per float4
        float* __restrict__ P) {
    __shared__ float xs[JCH];
    const int bid = blockIdx.x;
    const int b = bid >> 2;
    const int c = bid & 3;
    const int j0 = c * JCH;
    const int t = threadIdx.x;
    if (t < JCH) xs[t] = x[b * NN + j0 + t];
    __syncthreads();
    if (t >= NN / 2) return;

    const float2* __restrict__ u2 = (const float2*)(u + (size_t)b * NN * NN) + j0 * (NN / 2);
    const float4* __restrict__ wu = WU4 + j0 * (NN / 2);

    const float LO = 1e-6f;
    const float HI = (float)(1.0 - 1e-6);

    float acc0 = 0.0f, acc1 = 0.0f;
#pragma unroll 5
    for (int j = 0; j < JCH; ++j) {
        const int k = j * (NN / 2) + t;
        float2 uv = u2[k];
        float4 wv = wu[k];                 // (w0, U0, w1, U1)
        float  xj = xs[j];
        float uc0 = fminf(fmaxf(uv.x, LO), HI);
        float uc1 = fminf(fmaxf(uv.y, LO), HI);
        if (uc0 >= wv.y) acc0 += wv.x * xj;
        if (uc1 >= wv.w) acc1 += wv.z * xj;
    }
    float2 o = make_float2(acc0, acc1);
    ((float2*)(P + (size_t)c * BB * NN + b * NN))[t] = o;
}

// ---------------- reduce: sum 4 partials + tanh ------------------------------
__global__ __launch_bounds__(256) void reduce_kernel(const float* __restrict__ P,
                                                     float* __restrict__ out) {
    int n = blockIdx.x * blockDim.x + threadIdx.x;
    if (n >= BB * NN) return;
    const int S = BB * NN;
    float s = P[n] + P[S + n] + P[2 * S + n] + P[3 * S + n];
    out[n] = tanhf(s);
}

extern "C" void kernel_launch(void* const* d_in, const int* in_sizes, int n_in,
                              void* d_out, int out_size, void* d_ws, size_t ws_size,
                              hipStream_t stream) {
    const float* x  = (const float*)d_in[0];   // [B, N]
    const float* la = (const float*)d_in[1];   // [N, N]
    const float* W  = (const float*)d_in[2];   // [N, N]
    const float* u  = (const float*)d_in[3];   // [B, N, N]
    float* out = (float*)d_out;                // [B, N]

    float2* WU = (float2*)d_ws;                                  // 2,000,000 B
    float*  P  = (float*)((char*)d_ws + (size_t)NN * NN * sizeof(float2)); // 4,096,000 B

    int prep_blocks = (NN * NN + 255) / 256;
    prep_kernel<<<prep_blocks, 256, 0, stream>>>(la, W, WU);
    fused_kernel<<<BB * NCHUNK, 256, 0, stream>>>(x, u, (const float4*)WU, P);
    reduce_kernel<<<(BB * NN + 255) / 256, 256, 0, stream>>>(P, out);
}